// Round 5
// baseline (595.381 us; speedup 1.0000x reference)
//
#include <hip/hip_runtime.h>
#include <math.h>

// ---------------------------------------------------------------------------
// GraphSAGE 3-layer forward — R17: SINGLE persistent mega-kernel.
//  All 10 pipeline stages fused into one launch with device-wide generation
//  barriers (atomic cnt + gen flag, device-scope; cross-block visibility
//  pattern validated by R4's fused bscan). Co-residency from
//  hipOccupancyMaxActiveBlocksPerMultiprocessor; __launch_bounds__(512,4)
//  caps VGPR at 128 (transform<64,64> ~123 live regs).
//  Phases: {t1 ∥ hist} B {bscan} B {scatter} B {bucket_csr} B {agg1} B {t2}
//          B {agg2} B {t3} B {agg3}.  8 barriers, 2 dispatches (memset+mega).
//  bucketbase kernel eliminated: blocks rescan btot(<=256) into LDS locally.
//  - transforms: MFMA bf16 GEMM; y1l/y2l fp8 e4m3 payloads (R11/R12), y3l bf16.
//  - aggregates: sub-wave-per-node, unroll-4 + col prefetch (R16), src-quartile
//    row order (R15) keeps gather phase working set L2-resident.
// Assumes N <= 2^17, NBKT = ceil(N/512) <= 256.
// ---------------------------------------------------------------------------

typedef __attribute__((ext_vector_type(8))) short short8;
typedef __attribute__((ext_vector_type(4))) float floatx4;
typedef __attribute__((ext_vector_type(2))) float floatx2;

__device__ __forceinline__ unsigned short f2bf(float f) {   // RNE
    unsigned u = __float_as_uint(f);
    u += 0x7fffu + ((u >> 16) & 1u);
    return (unsigned short)(u >> 16);
}
__device__ __forceinline__ float blo(unsigned u) { return __uint_as_float(u << 16); }
__device__ __forceinline__ float bhi(unsigned u) { return __uint_as_float(u & 0xffff0000u); }
__device__ __forceinline__ unsigned char f2fp8(float f) {   // e4m3fn via HW
    return (unsigned char)(__builtin_amdgcn_cvt_pk_fp8_f32(f, f, 0, false) & 0xFF);
}

// ---- device-wide barrier (generation counter). Requires all blocks resident.
__device__ __forceinline__ void grid_barrier(int* cnt, int* gen, int nblk) {
    __syncthreads();
    if (threadIdx.x == 0) {
        __threadfence();
        const int g = __hip_atomic_load(gen, __ATOMIC_RELAXED, __HIP_MEMORY_SCOPE_AGENT);
        if (atomicAdd(cnt, 1) == nblk - 1) {
            __hip_atomic_store(cnt, 0, __ATOMIC_RELAXED, __HIP_MEMORY_SCOPE_AGENT);
            __hip_atomic_store(gen, g + 1, __ATOMIC_RELEASE, __HIP_MEMORY_SCOPE_AGENT);
        } else {
            while (__hip_atomic_load(gen, __ATOMIC_ACQUIRE, __HIP_MEMORY_SCOPE_AGENT) == g)
                __builtin_amdgcn_s_sleep(1);
        }
        __threadfence();
    }
    __syncthreads();
}

// ---- exclusive scan of btot[0..nbkt) into LDS lbase[0..nbkt] (512 threads)
__device__ void exscan_to_lds(const int* __restrict__ btot, int nbkt,
                              int* lbase, int* wscr) {
    __syncthreads();
    const int tid = threadIdx.x;
    const int lane = tid & 63, w = tid >> 6;
    const int v = (tid < nbkt) ? btot[tid] : 0;
    int incl = v;
#pragma unroll
    for (int off = 1; off < 64; off <<= 1) {
        const int t = __shfl_up(incl, off);
        if (lane >= off) incl += t;
    }
    if (lane == 63) wscr[w] = incl;
    __syncthreads();
    int base = 0;
#pragma unroll
    for (int ww = 0; ww < 8; ++ww) if (ww < w) base += wscr[ww];
    if (tid < nbkt) lbase[tid] = base + incl - v;
    if (tid == nbkt - 1) lbase[nbkt] = base + incl;
    __syncthreads();
}

// ---- MFMA transform phase: y_l = A@Wl (fp8|bf16), y_r = A@Wr+b (bf16) ------
template <int K, int F_OUT, int PAD, bool AFP32, bool YL8>
__device__ void transform_phase(
        const void* __restrict__ Ain, const float* __restrict__ Wl,
        const float* __restrict__ Wr, const float* __restrict__ bia,
        void* __restrict__ yl, unsigned short* __restrict__ yr,
        int n, int wid, int totw) {
    constexpr int KSTEP = K / 32;
    constexpr int NT = PAD / 16;
    const int lane = threadIdx.x & 63;
    const int nl = lane & 15, q = lane >> 4;
    const int ntiles = (n + 15) >> 4;

    short8 Bl[NT][KSTEP], Br[NT][KSTEP];
    float biasv[NT];
#pragma unroll
    for (int t = 0; t < NT; ++t) {
        const int ncol = t * 16 + nl;
        biasv[t] = (ncol < F_OUT) ? bia[ncol] : 0.f;
#pragma unroll
        for (int ks = 0; ks < KSTEP; ++ks) {
#pragma unroll
            for (int j = 0; j < 8; ++j) {
                const int k = ks * 32 + q * 8 + j;
                Bl[t][ks][j] = (ncol < F_OUT) ? (short)f2bf(Wl[k * F_OUT + ncol]) : (short)0;
                Br[t][ks][j] = (ncol < F_OUT) ? (short)f2bf(Wr[k * F_OUT + ncol]) : (short)0;
            }
        }
    }

    for (int t = wid; t < ntiles; t += totw) {
        const int m0 = t * 16;
        int m = m0 + nl; if (m >= n) m = n - 1;

        short8 a[KSTEP];
#pragma unroll
        for (int ks = 0; ks < KSTEP; ++ks) {
            if (AFP32) {
                const float* p = (const float*)Ain + (size_t)m * K + ks * 32 + q * 8;
#pragma unroll
                for (int j = 0; j < 8; ++j) a[ks][j] = (short)f2bf(p[j]);
            } else {
                union { uint4 u; short8 s; } cvt;
                cvt.u = *(const uint4*)((const unsigned short*)Ain + (size_t)m * K + ks * 32 + q * 8);
                a[ks] = cvt.s;
            }
        }

        floatx4 accl[NT], accr[NT];
#pragma unroll
        for (int tt = 0; tt < NT; ++tt) { accl[tt] = {0.f,0.f,0.f,0.f}; accr[tt] = {0.f,0.f,0.f,0.f}; }
#pragma unroll
        for (int ks = 0; ks < KSTEP; ++ks) {
#pragma unroll
            for (int tt = 0; tt < NT; ++tt) {
                accl[tt] = __builtin_amdgcn_mfma_f32_16x16x32_bf16(a[ks], Bl[tt][ks], accl[tt], 0, 0, 0);
                accr[tt] = __builtin_amdgcn_mfma_f32_16x16x32_bf16(a[ks], Br[tt][ks], accr[tt], 0, 0, 0);
            }
        }

#pragma unroll
        for (int tt = 0; tt < NT; ++tt) {
            const int ncol = tt * 16 + nl;
#pragma unroll
            for (int r = 0; r < 4; ++r) {
                const int node = m0 + q * 4 + r;
                if (node < n) {
                    if (YL8)
                        ((unsigned char*)yl)[(size_t)node * PAD + ncol] = f2fp8(accl[tt][r]);
                    else
                        ((unsigned short*)yl)[(size_t)node * PAD + ncol] = f2bf(accl[tt][r]);
                    yr[(size_t)node * PAD + ncol] = f2bf(accr[tt][r] + biasv[tt]);
                }
            }
        }
    }
}

// ---- aggregate phase: h = act(norm(mean_gather(yl) + yr)) ------------------
template <int F, int ACT, int PK>
__device__ void agg_phase(
        const void* __restrict__ yl, const unsigned short* __restrict__ yr,
        const int* __restrict__ rowptr, const int* __restrict__ degv,
        const int* __restrict__ col,
        unsigned short* __restrict__ hout, float* __restrict__ fout,
        int n, int wid, int totw) {
    constexpr int G = F / 8;
    constexpr int NPW = 64 / G;
    const int lane = threadIdx.x & 63;
    const int g = lane / G, c = lane % G;
    const int nw = (n + NPW - 1) / NPW;

    for (int w = wid; w < nw; w += totw) {
        const int node = w * NPW + g;
        if (node >= n) continue;

        const int beg = rowptr[node];
        const int dg  = degv[node];
        const int nmax = n - 1;

        float a0=0.f,a1=0.f,a2=0.f,a3=0.f,a4=0.f,a5=0.f,a6=0.f,a7=0.f;
        int i = 0;
        if (PK == 1) {
            const unsigned char* base = (const unsigned char*)yl + c * 8;
            auto accrow = [&](uint2 t) {
                const floatx2 p0 = __builtin_amdgcn_cvt_pk_f32_fp8((int)t.x, false);
                const floatx2 p1 = __builtin_amdgcn_cvt_pk_f32_fp8((int)t.x, true);
                const floatx2 p2 = __builtin_amdgcn_cvt_pk_f32_fp8((int)t.y, false);
                const floatx2 p3 = __builtin_amdgcn_cvt_pk_f32_fp8((int)t.y, true);
                a0 += p0.x; a1 += p0.y; a2 += p1.x; a3 += p1.y;
                a4 += p2.x; a5 += p2.y; a6 += p3.x; a7 += p3.y;
            };
            if (dg >= 4) {
                int c0 = col[beg], c1 = col[beg+1], c2 = col[beg+2], c3 = col[beg+3];
                for (; i + 8 <= dg; i += 4) {
                    const int d0 = col[beg+i+4], d1 = col[beg+i+5];
                    const int d2 = col[beg+i+6], d3 = col[beg+i+7];
                    const uint2 t0 = *(const uint2*)(base + (size_t)min(c0,nmax) * F);
                    const uint2 t1 = *(const uint2*)(base + (size_t)min(c1,nmax) * F);
                    const uint2 t2 = *(const uint2*)(base + (size_t)min(c2,nmax) * F);
                    const uint2 t3 = *(const uint2*)(base + (size_t)min(c3,nmax) * F);
                    accrow(t0); accrow(t1); accrow(t2); accrow(t3);
                    c0 = d0; c1 = d1; c2 = d2; c3 = d3;
                }
                const uint2 t0 = *(const uint2*)(base + (size_t)min(c0,nmax) * F);
                const uint2 t1 = *(const uint2*)(base + (size_t)min(c1,nmax) * F);
                const uint2 t2 = *(const uint2*)(base + (size_t)min(c2,nmax) * F);
                const uint2 t3 = *(const uint2*)(base + (size_t)min(c3,nmax) * F);
                accrow(t0); accrow(t1); accrow(t2); accrow(t3);
                i += 4;
            }
            for (; i < dg; ++i)
                accrow(*(const uint2*)(base + (size_t)min(col[beg+i],nmax) * F));
        } else {
            const unsigned short* base = (const unsigned short*)yl + c * 8;
            auto accrow4 = [&](uint4 t) {
                a0 += blo(t.x); a1 += bhi(t.x); a2 += blo(t.y); a3 += bhi(t.y);
                a4 += blo(t.z); a5 += bhi(t.z); a6 += blo(t.w); a7 += bhi(t.w);
            };
            if (dg >= 4) {
                int c0 = col[beg], c1 = col[beg+1], c2 = col[beg+2], c3 = col[beg+3];
                for (; i + 8 <= dg; i += 4) {
                    const int d0 = col[beg+i+4], d1 = col[beg+i+5];
                    const int d2 = col[beg+i+6], d3 = col[beg+i+7];
                    const uint4 t0 = *(const uint4*)(base + (size_t)min(c0,nmax) * F);
                    const uint4 t1 = *(const uint4*)(base + (size_t)min(c1,nmax) * F);
                    const uint4 t2 = *(const uint4*)(base + (size_t)min(c2,nmax) * F);
                    const uint4 t3 = *(const uint4*)(base + (size_t)min(c3,nmax) * F);
                    accrow4(t0); accrow4(t1); accrow4(t2); accrow4(t3);
                    c0 = d0; c1 = d1; c2 = d2; c3 = d3;
                }
                const uint4 t0 = *(const uint4*)(base + (size_t)min(c0,nmax) * F);
                const uint4 t1 = *(const uint4*)(base + (size_t)min(c1,nmax) * F);
                const uint4 t2 = *(const uint4*)(base + (size_t)min(c2,nmax) * F);
                const uint4 t3 = *(const uint4*)(base + (size_t)min(c3,nmax) * F);
                accrow4(t0); accrow4(t1); accrow4(t2); accrow4(t3);
                i += 4;
            }
            for (; i < dg; ++i)
                accrow4(*(const uint4*)(base + (size_t)min(col[beg+i],nmax) * F));
        }
        const float inv = (dg > 0) ? 1.f / (float)dg : 0.f;

        const uint4 rv = *(const uint4*)(yr + (size_t)node * F + c * 8);
        float o[8];
        o[0] = a0*inv + blo(rv.x); o[1] = a1*inv + bhi(rv.x);
        o[2] = a2*inv + blo(rv.y); o[3] = a3*inv + bhi(rv.y);
        o[4] = a4*inv + blo(rv.z); o[5] = a5*inv + bhi(rv.z);
        o[6] = a6*inv + blo(rv.w); o[7] = a7*inv + bhi(rv.w);

        float ss = 0.f;
#pragma unroll
        for (int j = 0; j < 8; ++j) ss += o[j] * o[j];
#pragma unroll
        for (int off = 1; off < G; off <<= 1) ss += __shfl_xor(ss, off);
        const float scale = 1.f / fmaxf(sqrtf(ss), 1e-12f);

        if (ACT == 1) {
            uint4 u;
            float h[8];
#pragma unroll
            for (int j = 0; j < 8; ++j) h[j] = fmaxf(o[j] * scale, 0.f);
            u.x = (unsigned)f2bf(h[0]) | ((unsigned)f2bf(h[1]) << 16);
            u.y = (unsigned)f2bf(h[2]) | ((unsigned)f2bf(h[3]) << 16);
            u.z = (unsigned)f2bf(h[4]) | ((unsigned)f2bf(h[5]) << 16);
            u.w = (unsigned)f2bf(h[6]) | ((unsigned)f2bf(h[7]) << 16);
            *(uint4*)(hout + (size_t)node * F + c * 8) = u;
        } else {
#pragma unroll
            for (int j = 0; j < 8; ++j) o[j] *= scale;
            const int cbase = c * 8;
            float m = -INFINITY;
#pragma unroll
            for (int j = 0; j < 8; ++j) if (cbase + j < 10) m = fmaxf(m, o[j]);
            m = fmaxf(m, __shfl_xor(m, 1));
            float s = 0.f;
#pragma unroll
            for (int j = 0; j < 8; ++j) if (cbase + j < 10) s += __expf(o[j] - m);
            s += __shfl_xor(s, 1);
            const float ls = logf(s);
#pragma unroll
            for (int j = 0; j < 8; ++j)
                if (cbase + j < 10) fout[(size_t)node * 10 + cbase + j] = o[j] - m - ls;
        }
    }
}

// ---- the mega-kernel -------------------------------------------------------
#define SMEM_BYTES 13376

__global__ __launch_bounds__(512, 4) void mega_kernel(
        const float* __restrict__ x, const int* __restrict__ ei,
        const float* __restrict__ W1l, const float* __restrict__ W1r, const float* __restrict__ b1,
        const float* __restrict__ W2l, const float* __restrict__ W2r, const float* __restrict__ b2,
        const float* __restrict__ W3l, const float* __restrict__ W3r, const float* __restrict__ b3,
        float* __restrict__ out,
        int* rowptr, int* deg, int* colidx, unsigned* ebuf,
        int* bh, int* offsb, int* btot, int* barcnt, int* bargen,
        unsigned char* y1l, unsigned short* y1r, unsigned short* h1,
        unsigned char* y2l, unsigned short* y2r, unsigned short* h2,
        unsigned short* y3l, unsigned short* y3r,
        int N, int E, int NBKT, int NB, int nblk) {
    __shared__ __align__(16) char smem[SMEM_BYTES];
    int* lh    = (int*)smem;                                 // hist: 256 ints
    unsigned long long* lcnt = (unsigned long long*)smem;    // csr: 512 u64
    int* lcur4 = (int*)(smem + 4096);                        // csr: 2048 ints
    int* lcurS = (int*)smem;                                 // scatter: 256 ints
    int* lbase = (int*)(smem + 12288);                       // 257 ints
    int* wscr  = (int*)(smem + 13320);                       // 8 ints

    const int blk = blockIdx.x, tid = threadIdx.x;
    const int wid  = (blk * 512 + tid) >> 6;   // global wave id
    const int totw = nblk * 8;

    // ---------------- P1: transform1  +  hist ----------------
    transform_phase<64, 64, 64, true, true>(x, W1l, W1r, b1, y1l, y1r, N, wid, totw);

    for (int chunk = blk; chunk < NB; chunk += nblk) {
        __syncthreads();
        if (tid < 256) lh[tid] = 0;
        __syncthreads();
        const int base = chunk << 12;
#pragma unroll
        for (int i = 0; i < 8; ++i) {
            const int e = base + (i << 9) + tid;
            if (e < E) atomicAdd(&lh[min((int)(((unsigned)ei[E + e]) >> 9), NBKT - 1)], 1);
        }
        __syncthreads();
        if (tid < NBKT) bh[tid * NB + chunk] = lh[tid];
    }
    grid_barrier(barcnt, bargen, nblk);

    // ---------------- P2: bscan (per-bucket chunk-scan -> offs, btot) -------
    {
        const int lane = tid & 63;
        for (int w = blk * 8 + (tid >> 6); w < NBKT; w += nblk * 8) {
            int running = 0;
            for (int base = 0; base < NB; base += 64) {
                const int j = base + lane;
                const int v = (j < NB) ? bh[w * NB + j] : 0;
                int incl = v;
#pragma unroll
                for (int off = 1; off < 64; off <<= 1) {
                    const int t = __shfl_up(incl, off);
                    if (lane >= off) incl += t;
                }
                if (j < NB) offsb[w * NB + j] = running + incl - v;
                running += __shfl(incl, 63);
            }
            if (lane == 0) btot[w] = running;
        }
    }
    grid_barrier(barcnt, bargen, nblk);

    // ---------------- P3: scatter (bucket_base recomputed in LDS) -----------
    exscan_to_lds(btot, NBKT, lbase, wscr);
    for (int chunk = blk; chunk < NB; chunk += nblk) {
        __syncthreads();
        if (tid < NBKT) lcurS[tid] = lbase[tid] + offsb[tid * NB + chunk];
        __syncthreads();
        const int base = chunk << 12;
#pragma unroll
        for (int i = 0; i < 8; ++i) {
            const int e = base + (i << 9) + tid;
            if (e < E) {
                const int s = ei[e];
                const unsigned d = (unsigned)ei[E + e];
                int p = atomicAdd(&lcurS[min((int)(d >> 9), NBKT - 1)], 1);
                p = min(p, E - 1);                       // defensive
                ebuf[p] = ((d & 511u) << 17) | (unsigned)s;
            }
        }
    }
    grid_barrier(barcnt, bargen, nblk);

    // ---------------- P4: bucket_csr (src-quartile 4-cursor order) ----------
    exscan_to_lds(btot, NBKT, lbase, wscr);
    {
        const int q1 = N >> 2, q2 = N >> 1, q3 = (N >> 2) + (N >> 1);
        const int lane = tid & 63, w = tid >> 6;
        for (int b = blk; b < NBKT; b += nblk) {
            const int segbase = lbase[b];
            const int L = lbase[b + 1] - segbase;
            __syncthreads();
            lcnt[tid] = 0ull;
            __syncthreads();
            for (int i = tid; i < L; i += 512) {
                const unsigned p = ebuf[segbase + i];
                const int ln = p >> 17;
                const int s  = (int)(p & 0x1FFFFu);
                const int q  = (s < q2) ? ((s < q1) ? 0 : 1) : ((s < q3) ? 2 : 3);
                atomicAdd(&lcnt[ln], 1ull << (q << 4));
            }
            __syncthreads();
            const unsigned long long cv = lcnt[tid];
            const int f0 = (int)(cv & 0xFFFFu),         f1 = (int)((cv >> 16) & 0xFFFFu);
            const int f2 = (int)((cv >> 32) & 0xFFFFu), f3 = (int)((cv >> 48) & 0xFFFFu);
            const int dnode = f0 + f1 + f2 + f3;
            int incl = dnode;
#pragma unroll
            for (int off = 1; off < 64; off <<= 1) {
                const int t = __shfl_up(incl, off);
                if (lane >= off) incl += t;
            }
            if (lane == 63) wscr[w] = incl;
            __syncthreads();
            int wbase = 0;
#pragma unroll
            for (int ww = 0; ww < 8; ++ww) if (ww < w) wbase += wscr[ww];
            const int excl = wbase + incl - dnode;
            const int node = (b << 9) + tid;
            if (node < N) { rowptr[node] = segbase + excl; deg[node] = dnode; }
            lcur4[tid]        = excl;
            lcur4[512 + tid]  = excl + f0;
            lcur4[1024 + tid] = excl + f0 + f1;
            lcur4[1536 + tid] = excl + f0 + f1 + f2;
            __syncthreads();
            for (int i = tid; i < L; i += 512) {
                const unsigned p = ebuf[segbase + i];
                const int ln = p >> 17;
                const int s  = (int)(p & 0x1FFFFu);
                const int q  = (s < q2) ? ((s < q1) ? 0 : 1) : ((s < q3) ? 2 : 3);
                int pos = atomicAdd(&lcur4[(q << 9) + ln], 1);
                pos = min(segbase + pos, E - 1);             // defensive
                colidx[pos] = s;
            }
        }
    }
    grid_barrier(barcnt, bargen, nblk);

    // ---------------- P5..P9: layers ----------------------------------------
    agg_phase<64, 1, 1>(y1l, y1r, rowptr, deg, colidx, h1, nullptr, N, wid, totw);
    grid_barrier(barcnt, bargen, nblk);

    transform_phase<64, 32, 32, false, true>(h1, W2l, W2r, b2, y2l, y2r, N, wid, totw);
    grid_barrier(barcnt, bargen, nblk);

    agg_phase<32, 1, 1>(y2l, y2r, rowptr, deg, colidx, h2, nullptr, N, wid, totw);
    grid_barrier(barcnt, bargen, nblk);

    transform_phase<32, 10, 16, false, false>(h2, W3l, W3r, b3, y3l, y3r, N, wid, totw);
    grid_barrier(barcnt, bargen, nblk);

    agg_phase<16, 2, 0>(y3l, y3r, rowptr, deg, colidx, nullptr, out, N, wid, totw);
}

extern "C" void kernel_launch(void* const* d_in, const int* in_sizes, int n_in,
                              void* d_out, int out_size, void* d_ws, size_t ws_size,
                              hipStream_t stream) {
    const float* x   = (const float*)d_in[0];
    const int*   ei  = (const int*)d_in[1];     // int64 in ref -> int32 on device
    const float* W1l = (const float*)d_in[2];
    const float* W1r = (const float*)d_in[3];
    const float* b1  = (const float*)d_in[4];
    const float* W2l = (const float*)d_in[5];
    const float* W2r = (const float*)d_in[6];
    const float* b2  = (const float*)d_in[7];
    const float* W3l = (const float*)d_in[8];
    const float* W3r = (const float*)d_in[9];
    const float* b3  = (const float*)d_in[10];
    float*       out = (float*)d_out;

    const int N = in_sizes[0] / 64;
    const int E = in_sizes[1] / 2;
    const int NBKT = (N + 511) >> 9;     // dst buckets of 512 nodes (<=256)
    const int NB   = (E + 4095) >> 12;   // 4096 edges per hist/scatter chunk

    auto align16 = [](size_t v) { return (v + 15) & ~(size_t)15; };
    char* ws = (char*)d_ws;
    size_t off = 0;
    int* rowptr  = (int*)(ws + off); off = align16(off + (size_t)N * 4);
    int* deg     = (int*)(ws + off); off = align16(off + (size_t)N * 4);
    int* colidx  = (int*)(ws + off); off = align16(off + (size_t)E * 4);
    unsigned* ebuf = (unsigned*)(ws + off); off = align16(off + (size_t)E * 4);
    int* bh      = (int*)(ws + off); off = align16(off + (size_t)NBKT * NB * 4);
    int* offsb   = (int*)(ws + off); off = align16(off + (size_t)NBKT * NB * 4);
    int* btot    = (int*)(ws + off); off = align16(off + (size_t)NBKT * 4);
    int* barmem  = (int*)(ws + off); off = align16(off + 16);
    unsigned char*  y1l = (unsigned char*)(ws + off);  off = align16(off + (size_t)N * 64);
    unsigned short* y1r = (unsigned short*)(ws + off); off = align16(off + (size_t)N * 64 * 2);
    unsigned short* h1  = (unsigned short*)(ws + off); off = align16(off + (size_t)N * 64 * 2);
    unsigned char*  y2l = (unsigned char*)(ws + off);  off = align16(off + (size_t)N * 32);
    unsigned short* y2r = (unsigned short*)(ws + off); off = align16(off + (size_t)N * 32 * 2);
    unsigned short* h2  = (unsigned short*)(ws + off); off = align16(off + (size_t)N * 32 * 2);
    unsigned short* y3l = (unsigned short*)(ws + off); off = align16(off + (size_t)N * 16 * 2);
    unsigned short* y3r = (unsigned short*)(ws + off); off = align16(off + (size_t)N * 16 * 2);
    (void)ws_size; (void)n_in; (void)out_size;

    // co-resident grid size (cached; MI355X has 256 CUs)
    static int nblk_cached = 0;
    if (nblk_cached == 0) {
        int bpc = 0;
        if (hipOccupancyMaxActiveBlocksPerMultiprocessor(&bpc, mega_kernel, 512, 0)
                != hipSuccess || bpc < 1) bpc = 1;
        if (bpc > 4) bpc = 4;
        nblk_cached = bpc * 256;
    }
    const int nblk = nblk_cached;

    hipMemsetAsync(barmem, 0, 8, stream);   // barrier cnt+gen
    mega_kernel<<<nblk, 512, 0, stream>>>(
        x, ei, W1l, W1r, b1, W2l, W2r, b2, W3l, W3r, b3, out,
        rowptr, deg, colidx, ebuf, bh, offsb, btot, barmem, barmem + 1,
        y1l, y1r, h1, y2l, y2r, h2, y3l, y3r,
        N, E, NBKT, NB, nblk);
}

// Round 6
// 594.612 us; speedup vs baseline: 1.0013x; 1.0013x over previous
//
#include <hip/hip_runtime.h>
#include <math.h>

// ---------------------------------------------------------------------------
// GraphSAGE 3-layer forward — R18: persistent mega-kernel, spill-free.
//  R17 post-mortem: launch_bounds(512,4) capped arch-VGPRs at 64; the hoisted
//  Bl/Br[NT][KSTEP] register arrays (64 VGPR for layer 1) spilled to scratch
//  (+~90MB HBM round-trip, VALUBusy 3%, 595us). R18 materializes B per
//  16-column tile INSIDE the tile loop (16 live VGPRs), converting from
//  L2-hot W on the fly (~2us device-wide VALU cost). Peak live regs ~70.
//  Barrier protocol unchanged from R17 (PASSED -> correctness proven).
//  Phases: {t1 ∥ hist} B {bscan} B {scatter} B {bucket_csr} B {agg1} B {t2}
//          B {agg2} B {t3} B {agg3}.  8 barriers, 2 dispatches (memset+mega).
//  - transforms: MFMA bf16 GEMM; y1l/y2l fp8 e4m3 payloads (R11/R12), y3l bf16.
//  - aggregates: sub-wave-per-node, unroll-4 + col prefetch (R16), src-quartile
//    row order (R15) keeps gather phase working set L2-resident.
// Assumes N <= 2^17, NBKT = ceil(N/512) <= 256.
// ---------------------------------------------------------------------------

typedef __attribute__((ext_vector_type(8))) short short8;
typedef __attribute__((ext_vector_type(4))) float floatx4;
typedef __attribute__((ext_vector_type(2))) float floatx2;

__device__ __forceinline__ unsigned short f2bf(float f) {   // RNE
    unsigned u = __float_as_uint(f);
    u += 0x7fffu + ((u >> 16) & 1u);
    return (unsigned short)(u >> 16);
}
__device__ __forceinline__ float blo(unsigned u) { return __uint_as_float(u << 16); }
__device__ __forceinline__ float bhi(unsigned u) { return __uint_as_float(u & 0xffff0000u); }
__device__ __forceinline__ unsigned char f2fp8(float f) {   // e4m3fn via HW
    return (unsigned char)(__builtin_amdgcn_cvt_pk_fp8_f32(f, f, 0, false) & 0xFF);
}

// ---- device-wide barrier (generation counter). Requires all blocks resident.
__device__ __forceinline__ void grid_barrier(int* cnt, int* gen, int nblk) {
    __syncthreads();
    if (threadIdx.x == 0) {
        __threadfence();
        const int g = __hip_atomic_load(gen, __ATOMIC_RELAXED, __HIP_MEMORY_SCOPE_AGENT);
        if (atomicAdd(cnt, 1) == nblk - 1) {
            __hip_atomic_store(cnt, 0, __ATOMIC_RELAXED, __HIP_MEMORY_SCOPE_AGENT);
            __hip_atomic_store(gen, g + 1, __ATOMIC_RELEASE, __HIP_MEMORY_SCOPE_AGENT);
        } else {
            while (__hip_atomic_load(gen, __ATOMIC_ACQUIRE, __HIP_MEMORY_SCOPE_AGENT) == g)
                __builtin_amdgcn_s_sleep(1);
        }
        __threadfence();
    }
    __syncthreads();
}

// ---- exclusive scan of btot[0..nbkt) into LDS lbase[0..nbkt] (512 threads)
__device__ void exscan_to_lds(const int* __restrict__ btot, int nbkt,
                              int* lbase, int* wscr) {
    __syncthreads();
    const int tid = threadIdx.x;
    const int lane = tid & 63, w = tid >> 6;
    const int v = (tid < nbkt) ? btot[tid] : 0;
    int incl = v;
#pragma unroll
    for (int off = 1; off < 64; off <<= 1) {
        const int t = __shfl_up(incl, off);
        if (lane >= off) incl += t;
    }
    if (lane == 63) wscr[w] = incl;
    __syncthreads();
    int base = 0;
#pragma unroll
    for (int ww = 0; ww < 8; ++ww) if (ww < w) base += wscr[ww];
    if (tid < nbkt) lbase[tid] = base + incl - v;
    if (tid == nbkt - 1) lbase[nbkt] = base + incl;
    __syncthreads();
}

// ---- MFMA transform phase: y_l = A@Wl (fp8|bf16), y_r = A@Wr+b (bf16) ------
// R18: B fragments built per 16-col tile (16 live VGPRs), not hoisted arrays.
template <int K, int F_OUT, int PAD, bool AFP32, bool YL8>
__device__ void transform_phase(
        const void* __restrict__ Ain, const float* __restrict__ Wl,
        const float* __restrict__ Wr, const float* __restrict__ bia,
        void* __restrict__ yl, unsigned short* __restrict__ yr,
        int n, int wid, int totw) {
    constexpr int KSTEP = K / 32;
    constexpr int NT = PAD / 16;
    const int lane = threadIdx.x & 63;
    const int nl = lane & 15, q = lane >> 4;
    const int ntiles = (n + 15) >> 4;

    for (int t = wid; t < ntiles; t += totw) {
        const int m0 = t * 16;
        int m = m0 + nl; if (m >= n) m = n - 1;

        short8 a[KSTEP];
#pragma unroll
        for (int ks = 0; ks < KSTEP; ++ks) {
            if (AFP32) {
                const float* p = (const float*)Ain + (size_t)m * K + ks * 32 + q * 8;
#pragma unroll
                for (int j = 0; j < 8; ++j) a[ks][j] = (short)f2bf(p[j]);
            } else {
                union { uint4 u; short8 s; } cvt;
                cvt.u = *(const uint4*)((const unsigned short*)Ain + (size_t)m * K + ks * 32 + q * 8);
                a[ks] = cvt.s;
            }
        }

#pragma unroll
        for (int tt = 0; tt < NT; ++tt) {
            const int ncol = tt * 16 + nl;
            const bool cok = (ncol < F_OUT);
            const float biasv = cok ? bia[ncol] : 0.f;
            floatx4 accl = {0.f,0.f,0.f,0.f}, accr = {0.f,0.f,0.f,0.f};
#pragma unroll
            for (int ks = 0; ks < KSTEP; ++ks) {
                short8 Bl, Br;
#pragma unroll
                for (int j = 0; j < 8; ++j) {
                    const int k = ks * 32 + q * 8 + j;
                    Bl[j] = cok ? (short)f2bf(Wl[k * F_OUT + ncol]) : (short)0;
                    Br[j] = cok ? (short)f2bf(Wr[k * F_OUT + ncol]) : (short)0;
                }
                accl = __builtin_amdgcn_mfma_f32_16x16x32_bf16(a[ks], Bl, accl, 0, 0, 0);
                accr = __builtin_amdgcn_mfma_f32_16x16x32_bf16(a[ks], Br, accr, 0, 0, 0);
            }
#pragma unroll
            for (int r = 0; r < 4; ++r) {
                const int node = m0 + q * 4 + r;
                if (node < n) {
                    if (YL8)
                        ((unsigned char*)yl)[(size_t)node * PAD + ncol] = f2fp8(accl[r]);
                    else
                        ((unsigned short*)yl)[(size_t)node * PAD + ncol] = f2bf(accl[r]);
                    yr[(size_t)node * PAD + ncol] = f2bf(accr[r] + biasv);
                }
            }
        }
    }
}

// ---- aggregate phase: h = act(norm(mean_gather(yl) + yr)) ------------------
template <int F, int ACT, int PK>
__device__ void agg_phase(
        const void* __restrict__ yl, const unsigned short* __restrict__ yr,
        const int* __restrict__ rowptr, const int* __restrict__ degv,
        const int* __restrict__ col,
        unsigned short* __restrict__ hout, float* __restrict__ fout,
        int n, int wid, int totw) {
    constexpr int G = F / 8;
    constexpr int NPW = 64 / G;
    const int lane = threadIdx.x & 63;
    const int g = lane / G, c = lane % G;
    const int nw = (n + NPW - 1) / NPW;

    for (int w = wid; w < nw; w += totw) {
        const int node = w * NPW + g;
        if (node >= n) continue;

        const int beg = rowptr[node];
        const int dg  = degv[node];
        const int nmax = n - 1;

        float a0=0.f,a1=0.f,a2=0.f,a3=0.f,a4=0.f,a5=0.f,a6=0.f,a7=0.f;
        int i = 0;
        if (PK == 1) {
            const unsigned char* base = (const unsigned char*)yl + c * 8;
            auto accrow = [&](uint2 t) {
                const floatx2 p0 = __builtin_amdgcn_cvt_pk_f32_fp8((int)t.x, false);
                const floatx2 p1 = __builtin_amdgcn_cvt_pk_f32_fp8((int)t.x, true);
                const floatx2 p2 = __builtin_amdgcn_cvt_pk_f32_fp8((int)t.y, false);
                const floatx2 p3 = __builtin_amdgcn_cvt_pk_f32_fp8((int)t.y, true);
                a0 += p0.x; a1 += p0.y; a2 += p1.x; a3 += p1.y;
                a4 += p2.x; a5 += p2.y; a6 += p3.x; a7 += p3.y;
            };
            if (dg >= 4) {
                int c0 = col[beg], c1 = col[beg+1], c2 = col[beg+2], c3 = col[beg+3];
                for (; i + 8 <= dg; i += 4) {
                    const int d0 = col[beg+i+4], d1 = col[beg+i+5];
                    const int d2 = col[beg+i+6], d3 = col[beg+i+7];
                    const uint2 t0 = *(const uint2*)(base + (size_t)min(c0,nmax) * F);
                    const uint2 t1 = *(const uint2*)(base + (size_t)min(c1,nmax) * F);
                    const uint2 t2 = *(const uint2*)(base + (size_t)min(c2,nmax) * F);
                    const uint2 t3 = *(const uint2*)(base + (size_t)min(c3,nmax) * F);
                    accrow(t0); accrow(t1); accrow(t2); accrow(t3);
                    c0 = d0; c1 = d1; c2 = d2; c3 = d3;
                }
                const uint2 t0 = *(const uint2*)(base + (size_t)min(c0,nmax) * F);
                const uint2 t1 = *(const uint2*)(base + (size_t)min(c1,nmax) * F);
                const uint2 t2 = *(const uint2*)(base + (size_t)min(c2,nmax) * F);
                const uint2 t3 = *(const uint2*)(base + (size_t)min(c3,nmax) * F);
                accrow(t0); accrow(t1); accrow(t2); accrow(t3);
                i += 4;
            }
            for (; i < dg; ++i)
                accrow(*(const uint2*)(base + (size_t)min(col[beg+i],nmax) * F));
        } else {
            const unsigned short* base = (const unsigned short*)yl + c * 8;
            auto accrow4 = [&](uint4 t) {
                a0 += blo(t.x); a1 += bhi(t.x); a2 += blo(t.y); a3 += bhi(t.y);
                a4 += blo(t.z); a5 += bhi(t.z); a6 += blo(t.w); a7 += bhi(t.w);
            };
            if (dg >= 4) {
                int c0 = col[beg], c1 = col[beg+1], c2 = col[beg+2], c3 = col[beg+3];
                for (; i + 8 <= dg; i += 4) {
                    const int d0 = col[beg+i+4], d1 = col[beg+i+5];
                    const int d2 = col[beg+i+6], d3 = col[beg+i+7];
                    const uint4 t0 = *(const uint4*)(base + (size_t)min(c0,nmax) * F);
                    const uint4 t1 = *(const uint4*)(base + (size_t)min(c1,nmax) * F);
                    const uint4 t2 = *(const uint4*)(base + (size_t)min(c2,nmax) * F);
                    const uint4 t3 = *(const uint4*)(base + (size_t)min(c3,nmax) * F);
                    accrow4(t0); accrow4(t1); accrow4(t2); accrow4(t3);
                    c0 = d0; c1 = d1; c2 = d2; c3 = d3;
                }
                const uint4 t0 = *(const uint4*)(base + (size_t)min(c0,nmax) * F);
                const uint4 t1 = *(const uint4*)(base + (size_t)min(c1,nmax) * F);
                const uint4 t2 = *(const uint4*)(base + (size_t)min(c2,nmax) * F);
                const uint4 t3 = *(const uint4*)(base + (size_t)min(c3,nmax) * F);
                accrow4(t0); accrow4(t1); accrow4(t2); accrow4(t3);
                i += 4;
            }
            for (; i < dg; ++i)
                accrow4(*(const uint4*)(base + (size_t)min(col[beg+i],nmax) * F));
        }
        const float inv = (dg > 0) ? 1.f / (float)dg : 0.f;

        const uint4 rv = *(const uint4*)(yr + (size_t)node * F + c * 8);
        float o[8];
        o[0] = a0*inv + blo(rv.x); o[1] = a1*inv + bhi(rv.x);
        o[2] = a2*inv + blo(rv.y); o[3] = a3*inv + bhi(rv.y);
        o[4] = a4*inv + blo(rv.z); o[5] = a5*inv + bhi(rv.z);
        o[6] = a6*inv + blo(rv.w); o[7] = a7*inv + bhi(rv.w);

        float ss = 0.f;
#pragma unroll
        for (int j = 0; j < 8; ++j) ss += o[j] * o[j];
#pragma unroll
        for (int off = 1; off < G; off <<= 1) ss += __shfl_xor(ss, off);
        const float scale = 1.f / fmaxf(sqrtf(ss), 1e-12f);

        if (ACT == 1) {
            uint4 u;
            float h[8];
#pragma unroll
            for (int j = 0; j < 8; ++j) h[j] = fmaxf(o[j] * scale, 0.f);
            u.x = (unsigned)f2bf(h[0]) | ((unsigned)f2bf(h[1]) << 16);
            u.y = (unsigned)f2bf(h[2]) | ((unsigned)f2bf(h[3]) << 16);
            u.z = (unsigned)f2bf(h[4]) | ((unsigned)f2bf(h[5]) << 16);
            u.w = (unsigned)f2bf(h[6]) | ((unsigned)f2bf(h[7]) << 16);
            *(uint4*)(hout + (size_t)node * F + c * 8) = u;
        } else {
#pragma unroll
            for (int j = 0; j < 8; ++j) o[j] *= scale;
            const int cbase = c * 8;
            float m = -INFINITY;
#pragma unroll
            for (int j = 0; j < 8; ++j) if (cbase + j < 10) m = fmaxf(m, o[j]);
            m = fmaxf(m, __shfl_xor(m, 1));
            float s = 0.f;
#pragma unroll
            for (int j = 0; j < 8; ++j) if (cbase + j < 10) s += __expf(o[j] - m);
            s += __shfl_xor(s, 1);
            const float ls = logf(s);
#pragma unroll
            for (int j = 0; j < 8; ++j)
                if (cbase + j < 10) fout[(size_t)node * 10 + cbase + j] = o[j] - m - ls;
        }
    }
}

// ---- the mega-kernel -------------------------------------------------------
#define SMEM_BYTES 13376

__global__ __launch_bounds__(512, 4) void mega_kernel(
        const float* __restrict__ x, const int* __restrict__ ei,
        const float* __restrict__ W1l, const float* __restrict__ W1r, const float* __restrict__ b1,
        const float* __restrict__ W2l, const float* __restrict__ W2r, const float* __restrict__ b2,
        const float* __restrict__ W3l, const float* __restrict__ W3r, const float* __restrict__ b3,
        float* __restrict__ out,
        int* rowptr, int* deg, int* colidx, unsigned* ebuf,
        int* bh, int* offsb, int* btot, int* barcnt, int* bargen,
        unsigned char* y1l, unsigned short* y1r, unsigned short* h1,
        unsigned char* y2l, unsigned short* y2r, unsigned short* h2,
        unsigned short* y3l, unsigned short* y3r,
        int N, int E, int NBKT, int NB, int nblk) {
    __shared__ __align__(16) char smem[SMEM_BYTES];
    int* lh    = (int*)smem;                                 // hist: 256 ints
    unsigned long long* lcnt = (unsigned long long*)smem;    // csr: 512 u64
    int* lcur4 = (int*)(smem + 4096);                        // csr: 2048 ints
    int* lcurS = (int*)smem;                                 // scatter: 256 ints
    int* lbase = (int*)(smem + 12288);                       // 257 ints
    int* wscr  = (int*)(smem + 13320);                       // 8 ints

    const int blk = blockIdx.x, tid = threadIdx.x;
    const int wid  = (blk * 512 + tid) >> 6;   // global wave id
    const int totw = nblk * 8;

    // ---------------- P1: transform1  +  hist ----------------
    transform_phase<64, 64, 64, true, true>(x, W1l, W1r, b1, y1l, y1r, N, wid, totw);

    for (int chunk = blk; chunk < NB; chunk += nblk) {
        __syncthreads();
        if (tid < 256) lh[tid] = 0;
        __syncthreads();
        const int base = chunk << 12;
#pragma unroll
        for (int i = 0; i < 8; ++i) {
            const int e = base + (i << 9) + tid;
            if (e < E) atomicAdd(&lh[min((int)(((unsigned)ei[E + e]) >> 9), NBKT - 1)], 1);
        }
        __syncthreads();
        if (tid < NBKT) bh[tid * NB + chunk] = lh[tid];
    }
    grid_barrier(barcnt, bargen, nblk);

    // ---------------- P2: bscan (per-bucket chunk-scan -> offs, btot) -------
    {
        const int lane = tid & 63;
        for (int w = blk * 8 + (tid >> 6); w < NBKT; w += nblk * 8) {
            int running = 0;
            for (int base = 0; base < NB; base += 64) {
                const int j = base + lane;
                const int v = (j < NB) ? bh[w * NB + j] : 0;
                int incl = v;
#pragma unroll
                for (int off = 1; off < 64; off <<= 1) {
                    const int t = __shfl_up(incl, off);
                    if (lane >= off) incl += t;
                }
                if (j < NB) offsb[w * NB + j] = running + incl - v;
                running += __shfl(incl, 63);
            }
            if (lane == 0) btot[w] = running;
        }
    }
    grid_barrier(barcnt, bargen, nblk);

    // ---------------- P3: scatter (bucket_base recomputed in LDS) -----------
    exscan_to_lds(btot, NBKT, lbase, wscr);
    for (int chunk = blk; chunk < NB; chunk += nblk) {
        __syncthreads();
        if (tid < NBKT) lcurS[tid] = lbase[tid] + offsb[tid * NB + chunk];
        __syncthreads();
        const int base = chunk << 12;
#pragma unroll
        for (int i = 0; i < 8; ++i) {
            const int e = base + (i << 9) + tid;
            if (e < E) {
                const int s = ei[e];
                const unsigned d = (unsigned)ei[E + e];
                int p = atomicAdd(&lcurS[min((int)(d >> 9), NBKT - 1)], 1);
                p = min(p, E - 1);                       // defensive
                ebuf[p] = ((d & 511u) << 17) | (unsigned)s;
            }
        }
    }
    grid_barrier(barcnt, bargen, nblk);

    // ---------------- P4: bucket_csr (src-quartile 4-cursor order) ----------
    exscan_to_lds(btot, NBKT, lbase, wscr);
    {
        const int q1 = N >> 2, q2 = N >> 1, q3 = (N >> 2) + (N >> 1);
        const int lane = tid & 63, w = tid >> 6;
        for (int b = blk; b < NBKT; b += nblk) {
            const int segbase = lbase[b];
            const int L = lbase[b + 1] - segbase;
            __syncthreads();
            lcnt[tid] = 0ull;
            __syncthreads();
            for (int i = tid; i < L; i += 512) {
                const unsigned p = ebuf[segbase + i];
                const int ln = p >> 17;
                const int s  = (int)(p & 0x1FFFFu);
                const int q  = (s < q2) ? ((s < q1) ? 0 : 1) : ((s < q3) ? 2 : 3);
                atomicAdd(&lcnt[ln], 1ull << (q << 4));
            }
            __syncthreads();
            const unsigned long long cv = lcnt[tid];
            const int f0 = (int)(cv & 0xFFFFu),         f1 = (int)((cv >> 16) & 0xFFFFu);
            const int f2 = (int)((cv >> 32) & 0xFFFFu), f3 = (int)((cv >> 48) & 0xFFFFu);
            const int dnode = f0 + f1 + f2 + f3;
            int incl = dnode;
#pragma unroll
            for (int off = 1; off < 64; off <<= 1) {
                const int t = __shfl_up(incl, off);
                if (lane >= off) incl += t;
            }
            if (lane == 63) wscr[w] = incl;
            __syncthreads();
            int wbase = 0;
#pragma unroll
            for (int ww = 0; ww < 8; ++ww) if (ww < w) wbase += wscr[ww];
            const int excl = wbase + incl - dnode;
            const int node = (b << 9) + tid;
            if (node < N) { rowptr[node] = segbase + excl; deg[node] = dnode; }
            lcur4[tid]        = excl;
            lcur4[512 + tid]  = excl + f0;
            lcur4[1024 + tid] = excl + f0 + f1;
            lcur4[1536 + tid] = excl + f0 + f1 + f2;
            __syncthreads();
            for (int i = tid; i < L; i += 512) {
                const unsigned p = ebuf[segbase + i];
                const int ln = p >> 17;
                const int s  = (int)(p & 0x1FFFFu);
                const int q  = (s < q2) ? ((s < q1) ? 0 : 1) : ((s < q3) ? 2 : 3);
                int pos = atomicAdd(&lcur4[(q << 9) + ln], 1);
                pos = min(segbase + pos, E - 1);             // defensive
                colidx[pos] = s;
            }
        }
    }
    grid_barrier(barcnt, bargen, nblk);

    // ---------------- P5..P9: layers ----------------------------------------
    agg_phase<64, 1, 1>(y1l, y1r, rowptr, deg, colidx, h1, nullptr, N, wid, totw);
    grid_barrier(barcnt, bargen, nblk);

    transform_phase<64, 32, 32, false, true>(h1, W2l, W2r, b2, y2l, y2r, N, wid, totw);
    grid_barrier(barcnt, bargen, nblk);

    agg_phase<32, 1, 1>(y2l, y2r, rowptr, deg, colidx, h2, nullptr, N, wid, totw);
    grid_barrier(barcnt, bargen, nblk);

    transform_phase<32, 10, 16, false, false>(h2, W3l, W3r, b3, y3l, y3r, N, wid, totw);
    grid_barrier(barcnt, bargen, nblk);

    agg_phase<16, 2, 0>(y3l, y3r, rowptr, deg, colidx, nullptr, out, N, wid, totw);
}

extern "C" void kernel_launch(void* const* d_in, const int* in_sizes, int n_in,
                              void* d_out, int out_size, void* d_ws, size_t ws_size,
                              hipStream_t stream) {
    const float* x   = (const float*)d_in[0];
    const int*   ei  = (const int*)d_in[1];     // int64 in ref -> int32 on device
    const float* W1l = (const float*)d_in[2];
    const float* W1r = (const float*)d_in[3];
    const float* b1  = (const float*)d_in[4];
    const float* W2l = (const float*)d_in[5];
    const float* W2r = (const float*)d_in[6];
    const float* b2  = (const float*)d_in[7];
    const float* W3l = (const float*)d_in[8];
    const float* W3r = (const float*)d_in[9];
    const float* b3  = (const float*)d_in[10];
    float*       out = (float*)d_out;

    const int N = in_sizes[0] / 64;
    const int E = in_sizes[1] / 2;
    const int NBKT = (N + 511) >> 9;     // dst buckets of 512 nodes (<=256)
    const int NB   = (E + 4095) >> 12;   // 4096 edges per hist/scatter chunk

    auto align16 = [](size_t v) { return (v + 15) & ~(size_t)15; };
    char* ws = (char*)d_ws;
    size_t off = 0;
    int* rowptr  = (int*)(ws + off); off = align16(off + (size_t)N * 4);
    int* deg     = (int*)(ws + off); off = align16(off + (size_t)N * 4);
    int* colidx  = (int*)(ws + off); off = align16(off + (size_t)E * 4);
    unsigned* ebuf = (unsigned*)(ws + off); off = align16(off + (size_t)E * 4);
    int* bh      = (int*)(ws + off); off = align16(off + (size_t)NBKT * NB * 4);
    int* offsb   = (int*)(ws + off); off = align16(off + (size_t)NBKT * NB * 4);
    int* btot    = (int*)(ws + off); off = align16(off + (size_t)NBKT * 4);
    int* barmem  = (int*)(ws + off); off = align16(off + 16);
    unsigned char*  y1l = (unsigned char*)(ws + off);  off = align16(off + (size_t)N * 64);
    unsigned short* y1r = (unsigned short*)(ws + off); off = align16(off + (size_t)N * 64 * 2);
    unsigned short* h1  = (unsigned short*)(ws + off); off = align16(off + (size_t)N * 64 * 2);
    unsigned char*  y2l = (unsigned char*)(ws + off);  off = align16(off + (size_t)N * 32);
    unsigned short* y2r = (unsigned short*)(ws + off); off = align16(off + (size_t)N * 32 * 2);
    unsigned short* h2  = (unsigned short*)(ws + off); off = align16(off + (size_t)N * 32 * 2);
    unsigned short* y3l = (unsigned short*)(ws + off); off = align16(off + (size_t)N * 16 * 2);
    unsigned short* y3r = (unsigned short*)(ws + off); off = align16(off + (size_t)N * 16 * 2);
    (void)ws_size; (void)n_in; (void)out_size;

    // co-resident grid size (cached; MI355X has 256 CUs)
    static int nblk_cached = 0;
    if (nblk_cached == 0) {
        int bpc = 0;
        if (hipOccupancyMaxActiveBlocksPerMultiprocessor(&bpc, mega_kernel, 512, 0)
                != hipSuccess || bpc < 1) bpc = 1;
        if (bpc > 4) bpc = 4;
        nblk_cached = bpc * 256;
    }
    const int nblk = nblk_cached;

    hipMemsetAsync(barmem, 0, 8, stream);   // barrier cnt+gen
    mega_kernel<<<nblk, 512, 0, stream>>>(
        x, ei, W1l, W1r, b1, W2l, W2r, b2, W3l, W3r, b3, out,
        rowptr, deg, colidx, ebuf, bh, offsb, btot, barmem, barmem + 1,
        y1l, y1r, h1, y2l, y2r, h2, y3l, y3r,
        N, E, NBKT, NB, nblk);
}

// Round 7
// 206.727 us; speedup vs baseline: 2.8800x; 2.8763x over previous
//
#include <hip/hip_runtime.h>
#include <math.h>

// ---------------------------------------------------------------------------
// GraphSAGE 3-layer forward — R19: R4 multi-kernel structure (212.3us proven)
//  + heterogeneous {scatter ∥ transform1} fusion (t1 is independent of the
//  CSR chain; blocks [0,NB) scatter, blocks [NB,..) transform — no new sync).
//  R17/R18 mega-kernel REVERTED: device-barrier persistent kernel ran 3x
//  slower with all pipes idle (VALUBusy 3%) — latency pathology, not spill.
//  - transforms: MFMA bf16 GEMM; y1l/y2l fp8 e4m3 payloads (R11/R12), y3l bf16.
//  - aggregates: sub-wave-per-node, unroll-4 + col prefetch (R16), src-quartile
//    row order (R15) keeps gather phase working set L2-resident.
//  - CSR build: atomic-free bucket sort; packed 64-bit quartile histogram +
//    wave-shfl scan (R16); bucketbase fused into bscan via last-block sync.
// Assumes N <= 2^17, NBKT = ceil(N/512) <= 256.
// ---------------------------------------------------------------------------

typedef __attribute__((ext_vector_type(8))) short short8;
typedef __attribute__((ext_vector_type(4))) float floatx4;
typedef __attribute__((ext_vector_type(2))) float floatx2;

__device__ __forceinline__ unsigned short f2bf(float f) {   // RNE
    unsigned u = __float_as_uint(f);
    u += 0x7fffu + ((u >> 16) & 1u);
    return (unsigned short)(u >> 16);
}
__device__ __forceinline__ float blo(unsigned u) { return __uint_as_float(u << 16); }
__device__ __forceinline__ float bhi(unsigned u) { return __uint_as_float(u & 0xffff0000u); }
__device__ __forceinline__ unsigned char f2fp8(float f) {   // e4m3fn via HW
    return (unsigned char)(__builtin_amdgcn_cvt_pk_fp8_f32(f, f, 0, false) & 0xFF);
}

// ---------------- CSR build (bucketed, atomic-free at global scope) ---------

__global__ __launch_bounds__(256) void hist_kernel(
        const int* __restrict__ ei, int* __restrict__ bh, int* __restrict__ sync_ctr,
        int E, int NB, int NBKT) {
    __shared__ int lh[256];
    const int tid = threadIdx.x, blk = blockIdx.x;
    if (blk == 0 && tid == 0) *sync_ctr = 0;   // for bscan last-block sync
    lh[tid] = 0;
    __syncthreads();
    const int base = blk << 12;
#pragma unroll
    for (int i = 0; i < 16; ++i) {
        const int e = base + (i << 8) + tid;
        if (e < E) atomicAdd(&lh[min((int)(((unsigned)ei[E + e]) >> 9), NBKT - 1)], 1);
    }
    __syncthreads();
    if (tid < NBKT) bh[tid * NB + blk] = lh[tid];
}

// bucketbase fused in via last-block pattern (device-scope atomic+fence).
__global__ __launch_bounds__(256) void bscan_kernel(
        const int* __restrict__ bh, int* __restrict__ offs, int* __restrict__ btot,
        int* __restrict__ bucket_base, int* __restrict__ sync_ctr,
        int NB, int NBKT) {
    const int lane = threadIdx.x & 63;
    const int w = blockIdx.x * 4 + (threadIdx.x >> 6);
    if (w < NBKT) {
        int running = 0;
        for (int base = 0; base < NB; base += 64) {
            const int j = base + lane;
            const int v = (j < NB) ? bh[w * NB + j] : 0;
            int incl = v;
#pragma unroll
            for (int off = 1; off < 64; off <<= 1) {
                const int t = __shfl_up(incl, off);
                if (lane >= off) incl += t;
            }
            if (j < NB) offs[w * NB + j] = running + incl - v;
            running += __shfl(incl, 63);
        }
        if (lane == 0) btot[w] = running;
    }
    __threadfence();                 // release btot/offs to device scope
    __syncthreads();
    __shared__ int amLast;
    if (threadIdx.x == 0) amLast = (atomicAdd(sync_ctr, 1) == (int)gridDim.x - 1);
    __syncthreads();
    if (amLast && threadIdx.x < 64) {
        __threadfence();             // acquire: other blocks' btot now visible
        int running = 0;
        for (int base = 0; base < NBKT; base += 64) {
            const int j = base + threadIdx.x;
            const int v = (j < NBKT) ? btot[j] : 0;
            int incl = v;
#pragma unroll
            for (int off = 1; off < 64; off <<= 1) {
                const int t = __shfl_up(incl, off);
                if ((int)threadIdx.x >= off) incl += t;
            }
            if (j < NBKT) bucket_base[j] = running + incl - v;
            running += __shfl(incl, 63);
        }
        if (threadIdx.x == 0) bucket_base[NBKT] = running;
    }
}

// ---- R19: heterogeneous fusion — blocks [0,NB) scatter, rest transform1 ----
template <int K, int F_OUT, int PAD, bool AFP32, bool YL8>
__global__ __launch_bounds__(256) void scatter_t1_kernel(
        const int* __restrict__ ei, const int* __restrict__ offs,
        const int* __restrict__ bucket_base, unsigned* __restrict__ ebuf,
        int E, int NB, int NBKT,
        const void* __restrict__ Ain, const float* __restrict__ Wl,
        const float* __restrict__ Wr, const float* __restrict__ b,
        void* __restrict__ yl, unsigned short* __restrict__ yr, int n) {
    __shared__ int lcur[256];
    const int tid = threadIdx.x;
    if ((int)blockIdx.x < NB) {
        // ---------------- scatter path ----------------
        const int blk = blockIdx.x;
        if (tid < NBKT) lcur[tid] = bucket_base[tid] + offs[tid * NB + blk];
        __syncthreads();
        const int base = blk << 12;
#pragma unroll
        for (int i = 0; i < 16; ++i) {
            const int e = base + (i << 8) + tid;
            if (e < E) {
                const int s = ei[e];
                const unsigned d = (unsigned)ei[E + e];
                int p = atomicAdd(&lcur[min((int)(d >> 9), NBKT - 1)], 1);
                p = min(p, E - 1);                       // defensive
                ebuf[p] = ((d & 511u) << 17) | (unsigned)s;
            }
        }
        return;
    }
    // ---------------- transform1 path ----------------
    constexpr int KSTEP = K / 32;
    constexpr int NT = PAD / 16;
    const int lane = tid & 63;
    const int wid = (((int)blockIdx.x - NB) * 256 + tid) >> 6;
    const int ntiles = (n + 15) >> 4;
    if (wid >= ntiles) return;
    const int nl = lane & 15, q = lane >> 4;

    short8 Bl[NT][KSTEP], Br[NT][KSTEP];
    float biasv[NT];
#pragma unroll
    for (int t = 0; t < NT; ++t) {
        const int ncol = t * 16 + nl;
        biasv[t] = (ncol < F_OUT) ? b[ncol] : 0.f;
#pragma unroll
        for (int ks = 0; ks < KSTEP; ++ks) {
#pragma unroll
            for (int j = 0; j < 8; ++j) {
                const int k = ks * 32 + q * 8 + j;
                Bl[t][ks][j] = (ncol < F_OUT) ? (short)f2bf(Wl[k * F_OUT + ncol]) : (short)0;
                Br[t][ks][j] = (ncol < F_OUT) ? (short)f2bf(Wr[k * F_OUT + ncol]) : (short)0;
            }
        }
    }

    const int m0 = wid * 16;
    int m = m0 + nl; if (m >= n) m = n - 1;

    short8 a[KSTEP];
#pragma unroll
    for (int ks = 0; ks < KSTEP; ++ks) {
        if (AFP32) {
            const float* p = (const float*)Ain + (size_t)m * K + ks * 32 + q * 8;
#pragma unroll
            for (int j = 0; j < 8; ++j) a[ks][j] = (short)f2bf(p[j]);
        } else {
            union { uint4 u; short8 s; } cvt;
            cvt.u = *(const uint4*)((const unsigned short*)Ain + (size_t)m * K + ks * 32 + q * 8);
            a[ks] = cvt.s;
        }
    }

    floatx4 accl[NT], accr[NT];
#pragma unroll
    for (int t = 0; t < NT; ++t) { accl[t] = {0.f,0.f,0.f,0.f}; accr[t] = {0.f,0.f,0.f,0.f}; }
#pragma unroll
    for (int ks = 0; ks < KSTEP; ++ks) {
#pragma unroll
        for (int t = 0; t < NT; ++t) {
            accl[t] = __builtin_amdgcn_mfma_f32_16x16x32_bf16(a[ks], Bl[t][ks], accl[t], 0, 0, 0);
            accr[t] = __builtin_amdgcn_mfma_f32_16x16x32_bf16(a[ks], Br[t][ks], accr[t], 0, 0, 0);
        }
    }

#pragma unroll
    for (int t = 0; t < NT; ++t) {
        const int ncol = t * 16 + nl;
#pragma unroll
        for (int r = 0; r < 4; ++r) {
            const int node = m0 + q * 4 + r;
            if (node < n) {
                if (YL8)
                    ((unsigned char*)yl)[(size_t)node * PAD + ncol] = f2fp8(accl[t][r]);
                else
                    ((unsigned short*)yl)[(size_t)node * PAD + ncol] = f2bf(accl[t][r]);
                yr[(size_t)node * PAD + ncol] = f2bf(accr[t][r] + biasv[t]);
            }
        }
    }
}

// R15/R16: four-cursor src-quartile ordering; pass-1 histogram = ONE packed
// 64-bit LDS atomic per edge (fields: 16 bits per quartile); wave-shfl scan.
__global__ __launch_bounds__(512) void bucket_csr_kernel(
        const unsigned* __restrict__ ebuf, const int* __restrict__ bucket_base,
        int* __restrict__ rowptr, int* __restrict__ deg, int* __restrict__ col,
        int N, int E) {
    __shared__ unsigned long long lcnt[512];
    __shared__ int lcur[2048]; // 4 cursors x 512 nodes
    __shared__ int wsum[8];
    const int b = blockIdx.x, tid = threadIdx.x;
    const int q1 = N >> 2, q2 = N >> 1, q3 = (N >> 2) + (N >> 1);
    const int segbase = bucket_base[b];
    const int L = bucket_base[b + 1] - segbase;
    lcnt[tid] = 0ull;
    __syncthreads();
    for (int i = tid; i < L; i += 512) {
        const unsigned p = ebuf[segbase + i];
        const int ln = p >> 17;
        const int s  = (int)(p & 0x1FFFFu);
        const int q  = (s < q2) ? ((s < q1) ? 0 : 1) : ((s < q3) ? 2 : 3);
        atomicAdd(&lcnt[ln], 1ull << (q << 4));
    }
    __syncthreads();
    const unsigned long long cv = lcnt[tid];
    const int f0 = (int)(cv & 0xFFFFu),         f1 = (int)((cv >> 16) & 0xFFFFu);
    const int f2 = (int)((cv >> 32) & 0xFFFFu), f3 = (int)((cv >> 48) & 0xFFFFu);
    const int dnode = f0 + f1 + f2 + f3;
    // block exclusive scan of dnode: per-wave shfl scan + wave-total combine
    const int lane = tid & 63, w = tid >> 6;
    int incl = dnode;
#pragma unroll
    for (int off = 1; off < 64; off <<= 1) {
        const int t = __shfl_up(incl, off);
        if (lane >= off) incl += t;
    }
    if (lane == 63) wsum[w] = incl;
    __syncthreads();
    int wbase = 0;
#pragma unroll
    for (int ww = 0; ww < 8; ++ww) if (ww < w) wbase += wsum[ww];
    const int excl = wbase + incl - dnode;
    const int node = (b << 9) + tid;
    if (node < N) { rowptr[node] = segbase + excl; deg[node] = dnode; }
    lcur[tid]        = excl;
    lcur[512 + tid]  = excl + f0;
    lcur[1024 + tid] = excl + f0 + f1;
    lcur[1536 + tid] = excl + f0 + f1 + f2;
    __syncthreads();
    for (int i = tid; i < L; i += 512) {
        const unsigned p = ebuf[segbase + i];
        const int ln = p >> 17;
        const int s  = (int)(p & 0x1FFFFu);
        const int q  = (s < q2) ? ((s < q1) ? 0 : 1) : ((s < q3) ? 2 : 3);
        int pos = atomicAdd(&lcur[(q << 9) + ln], 1);
        pos = min(segbase + pos, E - 1);             // defensive
        col[pos] = s;
    }
}

// ---------------- MFMA transform: y_l = A@Wl (fp8|bf16), y_r = A@Wr+b (bf16) -
template <int K, int F_OUT, int PAD, bool AFP32, bool YL8>
__global__ __launch_bounds__(256) void transform_kernel(
        const void* __restrict__ Ain, const float* __restrict__ Wl,
        const float* __restrict__ Wr, const float* __restrict__ b,
        void* __restrict__ yl, unsigned short* __restrict__ yr, int n) {
    constexpr int KSTEP = K / 32;
    constexpr int NT = PAD / 16;
    const int lane = threadIdx.x & 63;
    const int wid = (blockIdx.x * blockDim.x + threadIdx.x) >> 6;
    const int ntiles = (n + 15) >> 4;
    if (wid >= ntiles) return;
    const int nl = lane & 15, q = lane >> 4;

    short8 Bl[NT][KSTEP], Br[NT][KSTEP];
    float biasv[NT];
#pragma unroll
    for (int t = 0; t < NT; ++t) {
        const int ncol = t * 16 + nl;
        biasv[t] = (ncol < F_OUT) ? b[ncol] : 0.f;
#pragma unroll
        for (int ks = 0; ks < KSTEP; ++ks) {
#pragma unroll
            for (int j = 0; j < 8; ++j) {
                const int k = ks * 32 + q * 8 + j;
                Bl[t][ks][j] = (ncol < F_OUT) ? (short)f2bf(Wl[k * F_OUT + ncol]) : (short)0;
                Br[t][ks][j] = (ncol < F_OUT) ? (short)f2bf(Wr[k * F_OUT + ncol]) : (short)0;
            }
        }
    }

    const int m0 = wid * 16;
    int m = m0 + nl; if (m >= n) m = n - 1;

    short8 a[KSTEP];
#pragma unroll
    for (int ks = 0; ks < KSTEP; ++ks) {
        if (AFP32) {
            const float* p = (const float*)Ain + (size_t)m * K + ks * 32 + q * 8;
#pragma unroll
            for (int j = 0; j < 8; ++j) a[ks][j] = (short)f2bf(p[j]);
        } else {
            union { uint4 u; short8 s; } cvt;
            cvt.u = *(const uint4*)((const unsigned short*)Ain + (size_t)m * K + ks * 32 + q * 8);
            a[ks] = cvt.s;
        }
    }

    floatx4 accl[NT], accr[NT];
#pragma unroll
    for (int t = 0; t < NT; ++t) { accl[t] = {0.f,0.f,0.f,0.f}; accr[t] = {0.f,0.f,0.f,0.f}; }
#pragma unroll
    for (int ks = 0; ks < KSTEP; ++ks) {
#pragma unroll
        for (int t = 0; t < NT; ++t) {
            accl[t] = __builtin_amdgcn_mfma_f32_16x16x32_bf16(a[ks], Bl[t][ks], accl[t], 0, 0, 0);
            accr[t] = __builtin_amdgcn_mfma_f32_16x16x32_bf16(a[ks], Br[t][ks], accr[t], 0, 0, 0);
        }
    }

#pragma unroll
    for (int t = 0; t < NT; ++t) {
        const int ncol = t * 16 + nl;
#pragma unroll
        for (int r = 0; r < 4; ++r) {
            const int node = m0 + q * 4 + r;
            if (node < n) {
                if (YL8)
                    ((unsigned char*)yl)[(size_t)node * PAD + ncol] = f2fp8(accl[t][r]);
                else
                    ((unsigned short*)yl)[(size_t)node * PAD + ncol] = f2bf(accl[t][r]);
                yr[(size_t)node * PAD + ncol] = f2bf(accr[t][r] + biasv[t]);
            }
        }
    }
}

// ---------------- aggregate: h = act(norm(mean_gather(yl) + yr)) ------------
// R16: software-pipelined col prefetch — next quad's col indices load while
// current quad's payload gathers are outstanding (8 loads in flight).
// PK: 0 = bf16 payload (uint4/row-chunk), 1 = fp8 payload (uint2/row-chunk).
template <int F, int ACT, int PK>
__global__ __launch_bounds__(256) void agg_kernel(
        const void* __restrict__ yl, const unsigned short* __restrict__ yr,
        const int* __restrict__ rowptr, const int* __restrict__ degv,
        const int* __restrict__ col,
        unsigned short* __restrict__ hout, float* __restrict__ fout, int n) {
    constexpr int G = F / 8;
    constexpr int NPW = 64 / G;
    const int lane = threadIdx.x & 63;
    const int wid = (blockIdx.x * blockDim.x + threadIdx.x) >> 6;
    const int g = lane / G, c = lane % G;
    const int node = wid * NPW + g;
    if (node >= n) return;

    const int beg = rowptr[node];
    const int dg  = degv[node];
    const int nmax = n - 1;

    float a0=0.f,a1=0.f,a2=0.f,a3=0.f,a4=0.f,a5=0.f,a6=0.f,a7=0.f;
    int i = 0;
    if (PK == 1) {
        const unsigned char* base = (const unsigned char*)yl + c * 8;
        auto accrow = [&](uint2 t) {
            const floatx2 p0 = __builtin_amdgcn_cvt_pk_f32_fp8((int)t.x, false);
            const floatx2 p1 = __builtin_amdgcn_cvt_pk_f32_fp8((int)t.x, true);
            const floatx2 p2 = __builtin_amdgcn_cvt_pk_f32_fp8((int)t.y, false);
            const floatx2 p3 = __builtin_amdgcn_cvt_pk_f32_fp8((int)t.y, true);
            a0 += p0.x; a1 += p0.y; a2 += p1.x; a3 += p1.y;
            a4 += p2.x; a5 += p2.y; a6 += p3.x; a7 += p3.y;
        };
        if (dg >= 4) {
            int c0 = col[beg], c1 = col[beg+1], c2 = col[beg+2], c3 = col[beg+3];
            for (; i + 8 <= dg; i += 4) {
                const int d0 = col[beg+i+4], d1 = col[beg+i+5];
                const int d2 = col[beg+i+6], d3 = col[beg+i+7];
                const uint2 t0 = *(const uint2*)(base + (size_t)min(c0,nmax) * F);
                const uint2 t1 = *(const uint2*)(base + (size_t)min(c1,nmax) * F);
                const uint2 t2 = *(const uint2*)(base + (size_t)min(c2,nmax) * F);
                const uint2 t3 = *(const uint2*)(base + (size_t)min(c3,nmax) * F);
                accrow(t0); accrow(t1); accrow(t2); accrow(t3);
                c0 = d0; c1 = d1; c2 = d2; c3 = d3;
            }
            const uint2 t0 = *(const uint2*)(base + (size_t)min(c0,nmax) * F);
            const uint2 t1 = *(const uint2*)(base + (size_t)min(c1,nmax) * F);
            const uint2 t2 = *(const uint2*)(base + (size_t)min(c2,nmax) * F);
            const uint2 t3 = *(const uint2*)(base + (size_t)min(c3,nmax) * F);
            accrow(t0); accrow(t1); accrow(t2); accrow(t3);
            i += 4;
        }
        for (; i < dg; ++i)
            accrow(*(const uint2*)(base + (size_t)min(col[beg+i],nmax) * F));
    } else {
        const unsigned short* base = (const unsigned short*)yl + c * 8;
        auto accrow4 = [&](uint4 t) {
            a0 += blo(t.x); a1 += bhi(t.x); a2 += blo(t.y); a3 += bhi(t.y);
            a4 += blo(t.z); a5 += bhi(t.z); a6 += blo(t.w); a7 += bhi(t.w);
        };
        if (dg >= 4) {
            int c0 = col[beg], c1 = col[beg+1], c2 = col[beg+2], c3 = col[beg+3];
            for (; i + 8 <= dg; i += 4) {
                const int d0 = col[beg+i+4], d1 = col[beg+i+5];
                const int d2 = col[beg+i+6], d3 = col[beg+i+7];
                const uint4 t0 = *(const uint4*)(base + (size_t)min(c0,nmax) * F);
                const uint4 t1 = *(const uint4*)(base + (size_t)min(c1,nmax) * F);
                const uint4 t2 = *(const uint4*)(base + (size_t)min(c2,nmax) * F);
                const uint4 t3 = *(const uint4*)(base + (size_t)min(c3,nmax) * F);
                accrow4(t0); accrow4(t1); accrow4(t2); accrow4(t3);
                c0 = d0; c1 = d1; c2 = d2; c3 = d3;
            }
            const uint4 t0 = *(const uint4*)(base + (size_t)min(c0,nmax) * F);
            const uint4 t1 = *(const uint4*)(base + (size_t)min(c1,nmax) * F);
            const uint4 t2 = *(const uint4*)(base + (size_t)min(c2,nmax) * F);
            const uint4 t3 = *(const uint4*)(base + (size_t)min(c3,nmax) * F);
            accrow4(t0); accrow4(t1); accrow4(t2); accrow4(t3);
            i += 4;
        }
        for (; i < dg; ++i)
            accrow4(*(const uint4*)(base + (size_t)min(col[beg+i],nmax) * F));
    }
    const float inv = (dg > 0) ? 1.f / (float)dg : 0.f;

    // yr residual: bf16, coalesced
    const uint4 rv = *(const uint4*)(yr + (size_t)node * F + c * 8);
    float o[8];
    o[0] = a0*inv + blo(rv.x); o[1] = a1*inv + bhi(rv.x);
    o[2] = a2*inv + blo(rv.y); o[3] = a3*inv + bhi(rv.y);
    o[4] = a4*inv + blo(rv.z); o[5] = a5*inv + bhi(rv.z);
    o[6] = a6*inv + blo(rv.w); o[7] = a7*inv + bhi(rv.w);

    float ss = 0.f;
#pragma unroll
    for (int j = 0; j < 8; ++j) ss += o[j] * o[j];
#pragma unroll
    for (int off = 1; off < G; off <<= 1) ss += __shfl_xor(ss, off);
    const float scale = 1.f / fmaxf(sqrtf(ss), 1e-12f);

    if (ACT == 1) {
        uint4 u;
        float h[8];
#pragma unroll
        for (int j = 0; j < 8; ++j) h[j] = fmaxf(o[j] * scale, 0.f);
        u.x = (unsigned)f2bf(h[0]) | ((unsigned)f2bf(h[1]) << 16);
        u.y = (unsigned)f2bf(h[2]) | ((unsigned)f2bf(h[3]) << 16);
        u.z = (unsigned)f2bf(h[4]) | ((unsigned)f2bf(h[5]) << 16);
        u.w = (unsigned)f2bf(h[6]) | ((unsigned)f2bf(h[7]) << 16);
        *(uint4*)(hout + (size_t)node * F + c * 8) = u;
    } else {
#pragma unroll
        for (int j = 0; j < 8; ++j) o[j] *= scale;
        const int cbase = c * 8;
        float m = -INFINITY;
#pragma unroll
        for (int j = 0; j < 8; ++j) if (cbase + j < 10) m = fmaxf(m, o[j]);
        m = fmaxf(m, __shfl_xor(m, 1));
        float s = 0.f;
#pragma unroll
        for (int j = 0; j < 8; ++j) if (cbase + j < 10) s += __expf(o[j] - m);
        s += __shfl_xor(s, 1);
        const float ls = logf(s);
#pragma unroll
        for (int j = 0; j < 8; ++j)
            if (cbase + j < 10) fout[(size_t)node * 10 + cbase + j] = o[j] - m - ls;
    }
}

extern "C" void kernel_launch(void* const* d_in, const int* in_sizes, int n_in,
                              void* d_out, int out_size, void* d_ws, size_t ws_size,
                              hipStream_t stream) {
    const float* x   = (const float*)d_in[0];
    const int*   ei  = (const int*)d_in[1];     // int64 in ref -> int32 on device
    const float* W1l = (const float*)d_in[2];
    const float* W1r = (const float*)d_in[3];
    const float* b1  = (const float*)d_in[4];
    const float* W2l = (const float*)d_in[5];
    const float* W2r = (const float*)d_in[6];
    const float* b2  = (const float*)d_in[7];
    const float* W3l = (const float*)d_in[8];
    const float* W3r = (const float*)d_in[9];
    const float* b3  = (const float*)d_in[10];
    float*       out = (float*)d_out;

    const int N = in_sizes[0] / 64;
    const int E = in_sizes[1] / 2;
    const int NBKT = (N + 511) >> 9;     // dst buckets of 512 nodes (<=256)
    const int NB   = (E + 4095) >> 12;   // 4096 edges per hist/scatter block

    auto align16 = [](size_t v) { return (v + 15) & ~(size_t)15; };
    char* ws = (char*)d_ws;
    size_t off = 0;
    int* rowptr  = (int*)(ws + off); off = align16(off + (size_t)N * 4);
    int* deg     = (int*)(ws + off); off = align16(off + (size_t)N * 4);
    int* colidx  = (int*)(ws + off); off = align16(off + (size_t)E * 4);
    unsigned* ebuf = (unsigned*)(ws + off); off = align16(off + (size_t)E * 4);
    int* bh      = (int*)(ws + off); off = align16(off + (size_t)NBKT * NB * 4);
    int* offsb   = (int*)(ws + off); off = align16(off + (size_t)NBKT * NB * 4);
    int* btot    = (int*)(ws + off); off = align16(off + (size_t)NBKT * 4);
    int* bbase   = (int*)(ws + off); off = align16(off + (size_t)(NBKT + 1) * 4);
    int* sctr    = (int*)(ws + off); off = align16(off + 16);
    unsigned char*  y1l = (unsigned char*)(ws + off);  off = align16(off + (size_t)N * 64);
    unsigned short* y1r = (unsigned short*)(ws + off); off = align16(off + (size_t)N * 64 * 2);
    unsigned short* h1  = (unsigned short*)(ws + off); off = align16(off + (size_t)N * 64 * 2);
    unsigned char*  y2l = (unsigned char*)(ws + off);  off = align16(off + (size_t)N * 32);
    unsigned short* y2r = (unsigned short*)(ws + off); off = align16(off + (size_t)N * 32 * 2);
    unsigned short* h2  = (unsigned short*)(ws + off); off = align16(off + (size_t)N * 32 * 2);
    unsigned short* y3l = (unsigned short*)(ws + off); off = align16(off + (size_t)N * 16 * 2);
    unsigned short* y3r = (unsigned short*)(ws + off); off = align16(off + (size_t)N * 16 * 2);
    (void)ws_size; (void)n_in; (void)out_size;

    const int ntiles = (N + 15) / 16;                  // MFMA node tiles
    const int tblocks = (ntiles * 64 + 255) / 256;     // 4 waves/block

    // ---- CSR build; transform1 overlapped with scatter (independent work)
    hist_kernel<<<NB, 256, 0, stream>>>(ei, bh, sctr, E, NB, NBKT);
    bscan_kernel<<<(NBKT + 3) / 4, 256, 0, stream>>>(bh, offsb, btot, bbase, sctr, NB, NBKT);
    scatter_t1_kernel<64, 64, 64, true, true><<<NB + tblocks, 256, 0, stream>>>(
        ei, offsb, bbase, ebuf, E, NB, NBKT,
        x, W1l, W1r, b1, y1l, y1r, N);
    bucket_csr_kernel<<<NBKT, 512, 0, stream>>>(ebuf, bbase, rowptr, deg, colidx, N, E);

    // layer 1 (fp8 gather payload)
    agg_kernel<64, 1, 1><<<(N + 31) / 32, 256, 0, stream>>>(
        y1l, y1r, rowptr, deg, colidx, h1, nullptr, N);
    // layer 2 (fp8 gather payload)
    transform_kernel<64, 32, 32, false, true><<<tblocks, 256, 0, stream>>>(
        h1, W2l, W2r, b2, y2l, y2r, N);
    agg_kernel<32, 1, 1><<<(N + 63) / 64, 256, 0, stream>>>(
        y2l, y2r, rowptr, deg, colidx, h2, nullptr, N);
    // layer 3 (bf16 payload, L2-resident)
    transform_kernel<32, 10, 16, false, false><<<tblocks, 256, 0, stream>>>(
        h2, W3l, W3r, b3, y3l, y3r, N);
    agg_kernel<16, 2, 0><<<(N + 127) / 128, 256, 0, stream>>>(
        y3l, y3r, rowptr, deg, colidx, nullptr, out, N);
}